// Round 10
// baseline (298.504 us; speedup 1.0000x reference)
//
#include <hip/hip_runtime.h>

// ---------------------------------------------------------------------------
// SAGEConvNet round 9: gather v5 — b128 row loads (8 rows x 16B per wave
// instruction), csr stores pre-shifted byte offsets (s<<7).
// Everything else unchanged from R8 (prep'd bf16 W frags, proj2 v2, LDS-binned
// CSR build).
// ---------------------------------------------------------------------------

static inline size_t ws_align(size_t x) { return (x + 511) & ~size_t(511); }

#define MAXBC  104     // max coarse buckets supported (N <= 104*1024)
#define CAPL   96      // LDS slots per bucket per block (avg fill ~42)
#define EB_CAP 24576   // ebuf region capacity per bucket

using frag_ab = __attribute__((ext_vector_type(8))) short;   // 8 bf16
using f32x4   = __attribute__((ext_vector_type(4))) float;   // 4 fp32 acc
using us4     = __attribute__((ext_vector_type(4))) unsigned short;

__device__ inline short f2bf(float f) {            // RNE fp32 -> bf16
    unsigned u = __builtin_bit_cast(unsigned, f);
    u += 0x7fff + ((u >> 16) & 1);
    return (short)(u >> 16);
}
__device__ inline float b2f(unsigned short h) {
    unsigned u = ((unsigned)h) << 16;
    return __builtin_bit_cast(float, u);
}
__device__ inline float bflo(unsigned u) { return __builtin_bit_cast(float, u << 16); }
__device__ inline float bfhi(unsigned u) { return __builtin_bit_cast(float, u & 0xffff0000u); }

// ----------------------------- utility --------------------------------------

__global__ void zero_kernel(int* __restrict__ p, int n) {
    int i = blockIdx.x * blockDim.x + threadIdx.x;
    if (i < n) p[i] = 0;
}

// W -> bf16 B-frag layout. Per matrix (64 cols x F): fw[k>>3][col][k&7].
__global__ void prep_all(const float* __restrict__ W1l, const float* __restrict__ W1r,
                         const float* __restrict__ W2l, const float* __restrict__ W2r,
                         const float* __restrict__ W3l, const float* __restrict__ W3r,
                         unsigned short* __restrict__ fw) {
    const int idx = blockIdx.x * 256 + threadIdx.x;   // 0..32767
    if (idx >= 32768) return;
    const float* W;
    unsigned short* out;
    int F, rel;
    if (idx < 8192)       { W = W1l; out = fw;        F = 128; rel = idx; }
    else if (idx < 16384) { W = W1r; out = fw + 8192; F = 128; rel = idx - 8192; }
    else {
        const int q = (idx - 16384) >> 12;
        rel = (idx - 16384) & 4095;
        F = 64;
        W = (q == 0) ? W2l : (q == 1) ? W2r : (q == 2) ? W3l : W3r;
        out = fw + 16384 + q * 4096;
    }
    const int k = rel % F;                // rel = col*F + k
    const int col = rel / F;
    out[(k >> 3) * 512 + col * 8 + (k & 7)] = (unsigned short)f2bf(W[rel]);
}

// ----------------------------- CSR build ------------------------------------

__global__ void pass1_bin(const int* __restrict__ src, const int* __restrict__ dst,
                          int* __restrict__ bcur, unsigned* __restrict__ ebuf,
                          int nE, int nN, int nbc) {
    __shared__ unsigned lbuf[MAXBC][CAPL];
    __shared__ int bcnt[MAXBC];
    __shared__ int gbase[MAXBC];
    const int t = threadIdx.x;
    const int e0 = blockIdx.x * 4096;
    for (int i = t; i < MAXBC; i += 256) bcnt[i] = 0;
    __syncthreads();
#pragma unroll
    for (int q = 0; q < 16; ++q) {
        const int e = e0 + q * 256 + t;
        if (e < nE) {
            const unsigned d = (unsigned)dst[e];
            const unsigned s = (unsigned)src[e];
            if (d < (unsigned)nN && s < (unsigned)nN) {
                const int cb = (int)(d >> 10);
                const unsigned v = ((d & 1023u) << 17) | s;
                const int pos = atomicAdd(&bcnt[cb], 1);
                if (pos < CAPL) {
                    lbuf[cb][pos] = v;
                } else {
                    const int gp = atomicAdd(&bcur[cb], 1);
                    if (gp < EB_CAP) ebuf[(size_t)cb * EB_CAP + gp] = v;
                }
            }
        }
    }
    __syncthreads();
    for (int b = t; b < nbc; b += 256) {
        const int cnt = min(bcnt[b], CAPL);
        bcnt[b] = cnt;
        gbase[b] = (cnt > 0) ? atomicAdd(&bcur[b], cnt) : 0;
    }
    __syncthreads();
    const int wid = t >> 6, lane = t & 63;
    for (int b = wid; b < nbc; b += 4) {
        const int cnt = bcnt[b];
        const int gb = gbase[b];
        for (int i = lane; i < cnt; i += 64) {
            const int gp = gb + i;
            if (gp < EB_CAP) ebuf[(size_t)b * EB_CAP + gp] = lbuf[b][i];
        }
    }
}

__global__ void scan_buckets(const int* __restrict__ bcur, int* __restrict__ bbase, int nbc) {
    __shared__ int sdata[256];
    const int t = threadIdx.x;
    const int v = (t < nbc) ? min(bcur[t], EB_CAP) : 0;
    sdata[t] = v;
    __syncthreads();
    for (int off = 1; off < 256; off <<= 1) {
        int add = (t >= off) ? sdata[t - off] : 0;
        __syncthreads();
        sdata[t] += add;
        __syncthreads();
    }
    if (t < nbc) bbase[t] = sdata[t] - v;   // exclusive
}

// per-bucket: histogram -> rowptr, then csr scatter (stores s<<7 byte offsets).
__global__ void pass2_build(const unsigned* __restrict__ ebuf,
                            const int* __restrict__ bcur, const int* __restrict__ bbase,
                            int* __restrict__ rowptr, int* __restrict__ csr,
                            int nN, int nbc) {
    __shared__ int lcnt[1024];
    __shared__ int lcur[1024];
    __shared__ int sdata[256];
    const int b = blockIdx.x;
    const int node0 = b << 10;
    const int nloc = min(1024, nN - node0);
    if (nloc <= 0) return;
    const int cnt  = min(bcur[b], EB_CAP);
    const int base = bbase[b];
    const int t = threadIdx.x;
    const unsigned* eb = ebuf + (size_t)b * EB_CAP;

    for (int i = t; i < 1024; i += 256) lcnt[i] = 0;
    __syncthreads();
    for (int i = t; i < cnt; i += 256) atomicAdd(&lcnt[eb[i] >> 17], 1);
    __syncthreads();
    int v[4];
    int tsum = 0;
#pragma unroll
    for (int q = 0; q < 4; ++q) { v[q] = lcnt[t * 4 + q]; tsum += v[q]; }
    sdata[t] = tsum;
    __syncthreads();
    for (int off = 1; off < 256; off <<= 1) {
        int add = (t >= off) ? sdata[t - off] : 0;
        __syncthreads();
        sdata[t] += add;
        __syncthreads();
    }
    int run = sdata[t] - tsum;
#pragma unroll
    for (int q = 0; q < 4; ++q) {
        const int l = t * 4 + q;
        lcur[l] = run;
        if (l < nloc) rowptr[node0 + l] = base + run;
        run += v[q];
    }
    if (b == nbc - 1 && t == 0) rowptr[nN] = base + cnt;
    __syncthreads();
    for (int i = t; i < cnt; i += 256) {
        const unsigned ev = eb[i];
        const int pos = atomicAdd(&lcur[ev >> 17], 1);
        csr[base + pos] = (int)((ev & 0x1FFFFu) << 7);   // byte offset into xl
    }
}

// --------------------- dual projection via bf16 MFMA v2 ----------------------
template<int F, bool AF32>
__global__ void proj2_mfma(const void* __restrict__ Aptr,
                           const unsigned short* __restrict__ fwl,
                           const unsigned short* __restrict__ fwr,
                           const float* __restrict__ bias,
                           unsigned short* __restrict__ xl,  // bf16 [N][64]
                           float* __restrict__ xr,           // fp32 [N][64]
                           int nN) {
    const int t    = threadIdx.x;
    const int wave = t >> 6;
    const int lane = t & 63;
    const int lg   = lane >> 4;   // k-group (0..3)
    const int lr   = lane & 15;   // row (A) / col (B,C)
    const int row0 = blockIdx.x * 64 + wave * 16;

    const float*          Af = (const float*)Aptr;
    const unsigned short* Ab = (const unsigned short*)Aptr;

    f32x4 accl[4] = {};
    f32x4 accr[4] = {};

#pragma unroll
    for (int ks = 0; ks < F / 32; ++ks) {
        const int k0 = ks * 32 + lg * 8;
        frag_ab afr;
        {
            int row = row0 + lr;
            if (row >= nN) row = nN - 1;           // clamp; tail masked at store
            if constexpr (AF32) {
                const float4 f0 = *reinterpret_cast<const float4*>(Af + (size_t)row * F + k0);
                const float4 f1 = *reinterpret_cast<const float4*>(Af + (size_t)row * F + k0 + 4);
                afr[0] = f2bf(f0.x); afr[1] = f2bf(f0.y); afr[2] = f2bf(f0.z); afr[3] = f2bf(f0.w);
                afr[4] = f2bf(f1.x); afr[5] = f2bf(f1.y); afr[6] = f2bf(f1.z); afr[7] = f2bf(f1.w);
            } else {
                afr = *reinterpret_cast<const frag_ab*>(Ab + (size_t)row * F + k0);
            }
        }
        const int ob = (ks * 4 + lg) * 512;   // octet base in fw (64 cols x 8)
#pragma unroll
        for (int nf = 0; nf < 4; ++nf) {
            const int col = nf * 16 + lr;
            const frag_ab bl = *reinterpret_cast<const frag_ab*>(fwl + ob + col * 8);
            const frag_ab br = *reinterpret_cast<const frag_ab*>(fwr + ob + col * 8);
            accl[nf] = __builtin_amdgcn_mfma_f32_16x16x32_bf16(afr, bl, accl[nf], 0, 0, 0);
            accr[nf] = __builtin_amdgcn_mfma_f32_16x16x32_bf16(afr, br, accr[nf], 0, 0, 0);
        }
    }

    // C/D layout: col=lane&15, row=(lane>>4)*4+reg   [m89-verified]
#pragma unroll
    for (int nf = 0; nf < 4; ++nf) {
        const int col = nf * 16 + lr;
        const float bv = bias[col];
#pragma unroll
        for (int j = 0; j < 4; ++j) {
            const int row = row0 + lg * 4 + j;
            if (row < nN) {
                xl[(size_t)row * 64 + col] = (unsigned short)f2bf(accl[nf][j]);
                xr[(size_t)row * 64 + col] = accr[nf][j] + bv;
            }
        }
    }
}

// ----------------------------- gather-mean v5 --------------------------------
// one wave per node; lane = (rs=lane>>3 row-slot, fg=lane&7 feature-group).
// Per 16-edge batch: 1 csr vec load + 2 bpermute + 2 b128 row loads.
// csr holds byte offsets (s<<7). Reduce row-slots via shfl_xor(8/16/32).
template<bool DOELU>
__global__ void gather_kernel(const unsigned short* __restrict__ xl,
                              const float* __restrict__ xr,
                              const int* __restrict__ rowptr, const int* __restrict__ csr,
                              unsigned short* __restrict__ outp, int nN, int nE) {
    const int node = blockIdx.x * (blockDim.x >> 6) + (threadIdx.x >> 6);
    if (node >= nN) return;
    const int lane = threadIdx.x & 63;
    const int fg = lane & 7;        // feature group: bf16 features fg*8..fg*8+7
    const int rs = lane >> 3;       // row slot 0..7
    const unsigned fgo = (unsigned)(fg << 4);   // byte offset within row
    int b = rowptr[node];
    int e = rowptr[node + 1];
    b = max(0, min(b, nE));
    e = max(b, min(e, nE));
    const float d = (float)(e - b);
    const char* xlb = (const char*)xl;

    float acc[8] = {};
    int i = b;
    for (; i + 16 <= e; i += 16) {
        const int iv = csr[i + (lane & 15)];
        const int s0 = __shfl(iv, rs);          // edges i+rs
        const int s1 = __shfl(iv, 8 + rs);      // edges i+8+rs
        const uint4 u0 = *reinterpret_cast<const uint4*>(xlb + ((unsigned)s0 + fgo));
        const uint4 u1 = *reinterpret_cast<const uint4*>(xlb + ((unsigned)s1 + fgo));
        acc[0] += bflo(u0.x); acc[1] += bfhi(u0.x);
        acc[2] += bflo(u0.y); acc[3] += bfhi(u0.y);
        acc[4] += bflo(u0.z); acc[5] += bfhi(u0.z);
        acc[6] += bflo(u0.w); acc[7] += bfhi(u0.w);
        acc[0] += bflo(u1.x); acc[1] += bfhi(u1.x);
        acc[2] += bflo(u1.y); acc[3] += bfhi(u1.y);
        acc[4] += bflo(u1.z); acc[5] += bfhi(u1.z);
        acc[6] += bflo(u1.w); acc[7] += bfhi(u1.w);
    }
    if (i < e) {
        const int lim = e - i;                  // 1..15
        const int iv = csr[i + min(lane & 15, lim - 1)];
        const int s0 = __shfl(iv, min(rs, lim - 1));
        const int s1 = __shfl(iv, min(8 + rs, lim - 1));
        uint4 u0 = *reinterpret_cast<const uint4*>(xlb + ((unsigned)s0 + fgo));
        uint4 u1 = *reinterpret_cast<const uint4*>(xlb + ((unsigned)s1 + fgo));
        if (rs >= lim)     { u0.x = 0u; u0.y = 0u; u0.z = 0u; u0.w = 0u; }
        if (8 + rs >= lim) { u1.x = 0u; u1.y = 0u; u1.z = 0u; u1.w = 0u; }
        acc[0] += bflo(u0.x); acc[1] += bfhi(u0.x);
        acc[2] += bflo(u0.y); acc[3] += bfhi(u0.y);
        acc[4] += bflo(u0.z); acc[5] += bfhi(u0.z);
        acc[6] += bflo(u0.w); acc[7] += bfhi(u0.w);
        acc[0] += bflo(u1.x); acc[1] += bfhi(u1.x);
        acc[2] += bflo(u1.y); acc[3] += bfhi(u1.y);
        acc[4] += bflo(u1.z); acc[5] += bfhi(u1.z);
        acc[6] += bflo(u1.w); acc[7] += bfhi(u1.w);
    }

    // reduce the 8 row slots (lanes fg, fg+8, ..., fg+56)
#pragma unroll
    for (int k = 0; k < 8; ++k) acc[k] += __shfl_xor(acc[k], 8);
#pragma unroll
    for (int k = 0; k < 8; ++k) acc[k] += __shfl_xor(acc[k], 16);
#pragma unroll
    for (int k = 0; k < 8; ++k) acc[k] += __shfl_xor(acc[k], 32);

    if (rs == 0) {   // lanes 0..7: finish features fg*8..fg*8+7
        const float inv = 1.0f / fmaxf(d, 1.0f);
        const float4 r0 = *reinterpret_cast<const float4*>(xr + (size_t)node * 64 + fg * 8);
        const float4 r1 = *reinterpret_cast<const float4*>(xr + (size_t)node * 64 + fg * 8 + 4);
        float v[8];
        v[0] = acc[0] * inv + r0.x; v[1] = acc[1] * inv + r0.y;
        v[2] = acc[2] * inv + r0.z; v[3] = acc[3] * inv + r0.w;
        v[4] = acc[4] * inv + r1.x; v[5] = acc[5] * inv + r1.y;
        v[6] = acc[6] * inv + r1.z; v[7] = acc[7] * inv + r1.w;
        if (DOELU) {
#pragma unroll
            for (int k = 0; k < 8; ++k) v[k] = v[k] > 0.f ? v[k] : expm1f(v[k]);
        }
        uint4 p;
        p.x = ((unsigned)(unsigned short)f2bf(v[0])) | (((unsigned)(unsigned short)f2bf(v[1])) << 16);
        p.y = ((unsigned)(unsigned short)f2bf(v[2])) | (((unsigned)(unsigned short)f2bf(v[3])) << 16);
        p.z = ((unsigned)(unsigned short)f2bf(v[4])) | (((unsigned)(unsigned short)f2bf(v[5])) << 16);
        p.w = ((unsigned)(unsigned short)f2bf(v[6])) | (((unsigned)(unsigned short)f2bf(v[7])) << 16);
        *reinterpret_cast<uint4*>(outp + (size_t)node * 64 + fg * 8) = p;
    }
}

// ----------------------------- head (fp32 VALU, bf16 A) ----------------------
template<int F, int NOUT>
__global__ void head_kernel(const unsigned short* __restrict__ A,
                            const float* __restrict__ W,
                            const float* __restrict__ bias,
                            float* __restrict__ out, int nN) {
    constexpr int NCH = F / 32;
    __shared__ float As[64][36];
    __shared__ float Bs[32][64];

    const int t = threadIdx.x;
    const int block0 = blockIdx.x * 64;
    const int tm = (t >> 4) << 2;
    const int tn = (t & 15) << 2;

    float acc[4][4] = {};

    for (int ch = 0; ch < NCH; ++ch) {
        const int kg0 = ch * 32;
        {
            const int kk = (t & 7) * 4;
#pragma unroll
            for (int r = 0; r < 2; ++r) {
                const int n = (t >> 3) + r * 32;
                const int node = block0 + n;
                float4 v = make_float4(0.f, 0.f, 0.f, 0.f);
                if (node < nN) {
                    const us4 u = *reinterpret_cast<const us4*>(A + (size_t)node * F + kg0 + kk);
                    v.x = b2f(u[0]); v.y = b2f(u[1]); v.z = b2f(u[2]); v.w = b2f(u[3]);
                }
                *reinterpret_cast<float4*>(&As[n][kk]) = v;
            }
        }
        {
            const int j = t & 63;
#pragma unroll
            for (int p = 0; p < 8; ++p) {
                const int kk = (t >> 6) + p * 4;
                Bs[kk][j] = (j < NOUT) ? W[(size_t)j * F + kg0 + kk] : 0.0f;
            }
        }
        __syncthreads();
#pragma unroll
        for (int kk = 0; kk < 32; ++kk) {
            const float a0 = As[tm + 0][kk];
            const float a1 = As[tm + 1][kk];
            const float a2 = As[tm + 2][kk];
            const float a3 = As[tm + 3][kk];
            const float4 bv = *reinterpret_cast<const float4*>(&Bs[kk][tn]);
            acc[0][0] += a0 * bv.x; acc[0][1] += a0 * bv.y; acc[0][2] += a0 * bv.z; acc[0][3] += a0 * bv.w;
            acc[1][0] += a1 * bv.x; acc[1][1] += a1 * bv.y; acc[1][2] += a1 * bv.z; acc[1][3] += a1 * bv.w;
            acc[2][0] += a2 * bv.x; acc[2][1] += a2 * bv.y; acc[2][2] += a2 * bv.z; acc[2][3] += a2 * bv.w;
            acc[3][0] += a3 * bv.x; acc[3][1] += a3 * bv.y; acc[3][2] += a3 * bv.z; acc[3][3] += a3 * bv.w;
        }
        __syncthreads();
    }

#pragma unroll
    for (int i = 0; i < 4; ++i) {
        const int node = block0 + tm + i;
        if (node >= nN) continue;
#pragma unroll
        for (int j = 0; j < 4; ++j) {
            const int col = tn + j;
            if (col < NOUT)
                out[(size_t)node * NOUT + col] = acc[i][j] + bias[col];
        }
    }
}

// ----------------------------- launch ---------------------------------------

extern "C" void kernel_launch(void* const* d_in, const int* in_sizes, int n_in,
                              void* d_out, int out_size, void* d_ws, size_t ws_size,
                              hipStream_t stream) {
    const float* x    = (const float*)d_in[0];
    const int*   ei   = (const int*)d_in[1];
    const float* W1l  = (const float*)d_in[2];
    const float* b1   = (const float*)d_in[3];
    const float* W1r  = (const float*)d_in[4];
    const float* W2l  = (const float*)d_in[5];
    const float* b2   = (const float*)d_in[6];
    const float* W2r  = (const float*)d_in[7];
    const float* W3l  = (const float*)d_in[8];
    const float* b3   = (const float*)d_in[9];
    const float* W3r  = (const float*)d_in[10];
    const float* Wout = (const float*)d_in[11];
    const float* bout = (const float*)d_in[12];

    const int N = in_sizes[0] / 128;   // 100000
    const int E = in_sizes[1] / 2;     // 1600000
    const int* src  = ei;
    const int* dstA = ei + E;
    const int nbc = (N + 1023) >> 10;

    char* ws = (char*)d_ws;
    size_t o = 0;
    int* bcur    = (int*)(ws + o); o += ws_align((size_t)MAXBC * 4);
    int* bbase   = (int*)(ws + o); o += ws_align((size_t)MAXBC * 4);
    int* rowptr  = (int*)(ws + o); o += ws_align((size_t)(N + 1) * 4);
    int* csr     = (int*)(ws + o); o += ws_align((size_t)E * 4);
    unsigned* ebuf = (unsigned*)(ws + o); o += ws_align((size_t)MAXBC * EB_CAP * 4);
    unsigned short* fw  = (unsigned short*)(ws + o); o += ws_align((size_t)32768 * 2);
    unsigned short* xl  = (unsigned short*)(ws + o); o += ws_align((size_t)N * 64 * 2);
    float*          xr  = (float*)(ws + o);          o += ws_align((size_t)N * 64 * 4);
    unsigned short* hAb = (unsigned short*)(ws + o); o += ws_align((size_t)N * 64 * 2);
    unsigned short* hBb = (unsigned short*)(ws + o); o += ws_align((size_t)N * 64 * 2);
    unsigned short* h3b = (unsigned short*)(ws + o); o += ws_align((size_t)N * 64 * 2);
    float* outp = (float*)d_out;

    const int projGrid = (N + 63) / 64;
    const int gatherGrid = (N + 3) / 4;
    const int headGrid = (N + 63) / 64;

    // ---- weight prep + CSR build ----
    zero_kernel<<<1, 256, 0, stream>>>(bcur, MAXBC);
    prep_all<<<128, 256, 0, stream>>>(W1l, W1r, W2l, W2r, W3l, W3r, fw);
    pass1_bin<<<(E + 4095) / 4096, 256, 0, stream>>>(src, dstA, bcur, ebuf, E, N, nbc);
    scan_buckets<<<1, 256, 0, stream>>>(bcur, bbase, nbc);
    pass2_build<<<nbc, 256, 0, stream>>>(ebuf, bcur, bbase, rowptr, csr, N, nbc);

    const unsigned short* fw1l = fw;
    const unsigned short* fw1r = fw + 8192;
    const unsigned short* fw2l = fw + 16384;
    const unsigned short* fw2r = fw + 16384 + 4096;
    const unsigned short* fw3l = fw + 16384 + 8192;
    const unsigned short* fw3r = fw + 16384 + 12288;

    // ---- layer 1 (128 -> 64, ELU) ----
    proj2_mfma<128, true><<<projGrid, 256, 0, stream>>>(x, fw1l, fw1r, b1, xl, xr, N);
    gather_kernel<true><<<gatherGrid, 256, 0, stream>>>(xl, xr, rowptr, csr, hAb, N, E);

    // ---- layer 2 (64 -> 64, ELU) ----
    proj2_mfma<64, false><<<projGrid, 256, 0, stream>>>(hAb, fw2l, fw2r, b2, xl, xr, N);
    gather_kernel<true><<<gatherGrid, 256, 0, stream>>>(xl, xr, rowptr, csr, hBb, N, E);

    // ---- layer 3 (64 -> 64, no ELU) ----
    proj2_mfma<64, false><<<projGrid, 256, 0, stream>>>(hBb, fw3l, fw3r, b3, xl, xr, N);
    gather_kernel<false><<<gatherGrid, 256, 0, stream>>>(xl, xr, rowptr, csr, h3b, N, E);

    // ---- head (64 -> 40, fp32 math, bf16 input) ----
    head_kernel<64, 40><<<headGrid, 256, 0, stream>>>(h3b, Wout, bout, outp, N);
}

// Round 11
// 274.542 us; speedup vs baseline: 1.0873x; 1.0873x over previous
//
#include <hip/hip_runtime.h>

// ---------------------------------------------------------------------------
// SAGEConvNet round 10: gather v6 — v4 structure (lane=feature, one 128B line
// per load) + scalar-pipe index fetch (s_load csr via wave-uniform addresses,
// SGPR base adds). csr holds byte offsets (src<<7). Rest unchanged from R9.
// ---------------------------------------------------------------------------

static inline size_t ws_align(size_t x) { return (x + 511) & ~size_t(511); }

#define MAXBC  104     // max coarse buckets supported (N <= 104*1024)
#define CAPL   96      // LDS slots per bucket per block (avg fill ~42)
#define EB_CAP 24576   // ebuf region capacity per bucket

using frag_ab = __attribute__((ext_vector_type(8))) short;   // 8 bf16
using f32x4   = __attribute__((ext_vector_type(4))) float;   // 4 fp32 acc
using us4     = __attribute__((ext_vector_type(4))) unsigned short;

__device__ inline short f2bf(float f) {            // RNE fp32 -> bf16
    unsigned u = __builtin_bit_cast(unsigned, f);
    u += 0x7fff + ((u >> 16) & 1);
    return (short)(u >> 16);
}
__device__ inline float b2f(unsigned short h) {
    unsigned u = ((unsigned)h) << 16;
    return __builtin_bit_cast(float, u);
}

// ----------------------------- utility --------------------------------------

__global__ void zero_kernel(int* __restrict__ p, int n) {
    int i = blockIdx.x * blockDim.x + threadIdx.x;
    if (i < n) p[i] = 0;
}

// W -> bf16 B-frag layout. Per matrix (64 cols x F): fw[k>>3][col][k&7].
__global__ void prep_all(const float* __restrict__ W1l, const float* __restrict__ W1r,
                         const float* __restrict__ W2l, const float* __restrict__ W2r,
                         const float* __restrict__ W3l, const float* __restrict__ W3r,
                         unsigned short* __restrict__ fw) {
    const int idx = blockIdx.x * 256 + threadIdx.x;   // 0..32767
    if (idx >= 32768) return;
    const float* W;
    unsigned short* out;
    int F, rel;
    if (idx < 8192)       { W = W1l; out = fw;        F = 128; rel = idx; }
    else if (idx < 16384) { W = W1r; out = fw + 8192; F = 128; rel = idx - 8192; }
    else {
        const int q = (idx - 16384) >> 12;
        rel = (idx - 16384) & 4095;
        F = 64;
        W = (q == 0) ? W2l : (q == 1) ? W2r : (q == 2) ? W3l : W3r;
        out = fw + 16384 + q * 4096;
    }
    const int k = rel % F;                // rel = col*F + k
    const int col = rel / F;
    out[(k >> 3) * 512 + col * 8 + (k & 7)] = (unsigned short)f2bf(W[rel]);
}

// ----------------------------- CSR build ------------------------------------

__global__ void pass1_bin(const int* __restrict__ src, const int* __restrict__ dst,
                          int* __restrict__ bcur, unsigned* __restrict__ ebuf,
                          int nE, int nN, int nbc) {
    __shared__ unsigned lbuf[MAXBC][CAPL];
    __shared__ int bcnt[MAXBC];
    __shared__ int gbase[MAXBC];
    const int t = threadIdx.x;
    const int e0 = blockIdx.x * 4096;
    for (int i = t; i < MAXBC; i += 256) bcnt[i] = 0;
    __syncthreads();
#pragma unroll
    for (int q = 0; q < 16; ++q) {
        const int e = e0 + q * 256 + t;
        if (e < nE) {
            const unsigned d = (unsigned)dst[e];
            const unsigned s = (unsigned)src[e];
            if (d < (unsigned)nN && s < (unsigned)nN) {
                const int cb = (int)(d >> 10);
                const unsigned v = ((d & 1023u) << 17) | s;
                const int pos = atomicAdd(&bcnt[cb], 1);
                if (pos < CAPL) {
                    lbuf[cb][pos] = v;
                } else {
                    const int gp = atomicAdd(&bcur[cb], 1);
                    if (gp < EB_CAP) ebuf[(size_t)cb * EB_CAP + gp] = v;
                }
            }
        }
    }
    __syncthreads();
    for (int b = t; b < nbc; b += 256) {
        const int cnt = min(bcnt[b], CAPL);
        bcnt[b] = cnt;
        gbase[b] = (cnt > 0) ? atomicAdd(&bcur[b], cnt) : 0;
    }
    __syncthreads();
    const int wid = t >> 6, lane = t & 63;
    for (int b = wid; b < nbc; b += 4) {
        const int cnt = bcnt[b];
        const int gb = gbase[b];
        for (int i = lane; i < cnt; i += 64) {
            const int gp = gb + i;
            if (gp < EB_CAP) ebuf[(size_t)b * EB_CAP + gp] = lbuf[b][i];
        }
    }
}

__global__ void scan_buckets(const int* __restrict__ bcur, int* __restrict__ bbase, int nbc) {
    __shared__ int sdata[256];
    const int t = threadIdx.x;
    const int v = (t < nbc) ? min(bcur[t], EB_CAP) : 0;
    sdata[t] = v;
    __syncthreads();
    for (int off = 1; off < 256; off <<= 1) {
        int add = (t >= off) ? sdata[t - off] : 0;
        __syncthreads();
        sdata[t] += add;
        __syncthreads();
    }
    if (t < nbc) bbase[t] = sdata[t] - v;   // exclusive
}

// per-bucket: histogram -> rowptr, then csr scatter (stores s<<7 byte offsets).
__global__ void pass2_build(const unsigned* __restrict__ ebuf,
                            const int* __restrict__ bcur, const int* __restrict__ bbase,
                            int* __restrict__ rowptr, int* __restrict__ csr,
                            int nN, int nbc) {
    __shared__ int lcnt[1024];
    __shared__ int lcur[1024];
    __shared__ int sdata[256];
    const int b = blockIdx.x;
    const int node0 = b << 10;
    const int nloc = min(1024, nN - node0);
    if (nloc <= 0) return;
    const int cnt  = min(bcur[b], EB_CAP);
    const int base = bbase[b];
    const int t = threadIdx.x;
    const unsigned* eb = ebuf + (size_t)b * EB_CAP;

    for (int i = t; i < 1024; i += 256) lcnt[i] = 0;
    __syncthreads();
    for (int i = t; i < cnt; i += 256) atomicAdd(&lcnt[eb[i] >> 17], 1);
    __syncthreads();
    int v[4];
    int tsum = 0;
#pragma unroll
    for (int q = 0; q < 4; ++q) { v[q] = lcnt[t * 4 + q]; tsum += v[q]; }
    sdata[t] = tsum;
    __syncthreads();
    for (int off = 1; off < 256; off <<= 1) {
        int add = (t >= off) ? sdata[t - off] : 0;
        __syncthreads();
        sdata[t] += add;
        __syncthreads();
    }
    int run = sdata[t] - tsum;
#pragma unroll
    for (int q = 0; q < 4; ++q) {
        const int l = t * 4 + q;
        lcur[l] = run;
        if (l < nloc) rowptr[node0 + l] = base + run;
        run += v[q];
    }
    if (b == nbc - 1 && t == 0) rowptr[nN] = base + cnt;
    __syncthreads();
    for (int i = t; i < cnt; i += 256) {
        const unsigned ev = eb[i];
        const int pos = atomicAdd(&lcur[ev >> 17], 1);
        csr[base + pos] = (int)((ev & 0x1FFFFu) << 7);   // byte offset into xl
    }
}

// --------------------- dual projection via bf16 MFMA v2 ----------------------
template<int F, bool AF32>
__global__ void proj2_mfma(const void* __restrict__ Aptr,
                           const unsigned short* __restrict__ fwl,
                           const unsigned short* __restrict__ fwr,
                           const float* __restrict__ bias,
                           unsigned short* __restrict__ xl,  // bf16 [N][64]
                           float* __restrict__ xr,           // fp32 [N][64]
                           int nN) {
    const int t    = threadIdx.x;
    const int wave = t >> 6;
    const int lane = t & 63;
    const int lg   = lane >> 4;   // k-group (0..3)
    const int lr   = lane & 15;   // row (A) / col (B,C)
    const int row0 = blockIdx.x * 64 + wave * 16;

    const float*          Af = (const float*)Aptr;
    const unsigned short* Ab = (const unsigned short*)Aptr;

    f32x4 accl[4] = {};
    f32x4 accr[4] = {};

#pragma unroll
    for (int ks = 0; ks < F / 32; ++ks) {
        const int k0 = ks * 32 + lg * 8;
        frag_ab afr;
        {
            int row = row0 + lr;
            if (row >= nN) row = nN - 1;           // clamp; tail masked at store
            if constexpr (AF32) {
                const float4 f0 = *reinterpret_cast<const float4*>(Af + (size_t)row * F + k0);
                const float4 f1 = *reinterpret_cast<const float4*>(Af + (size_t)row * F + k0 + 4);
                afr[0] = f2bf(f0.x); afr[1] = f2bf(f0.y); afr[2] = f2bf(f0.z); afr[3] = f2bf(f0.w);
                afr[4] = f2bf(f1.x); afr[5] = f2bf(f1.y); afr[6] = f2bf(f1.z); afr[7] = f2bf(f1.w);
            } else {
                afr = *reinterpret_cast<const frag_ab*>(Ab + (size_t)row * F + k0);
            }
        }
        const int ob = (ks * 4 + lg) * 512;   // octet base in fw (64 cols x 8)
#pragma unroll
        for (int nf = 0; nf < 4; ++nf) {
            const int col = nf * 16 + lr;
            const frag_ab bl = *reinterpret_cast<const frag_ab*>(fwl + ob + col * 8);
            const frag_ab br = *reinterpret_cast<const frag_ab*>(fwr + ob + col * 8);
            accl[nf] = __builtin_amdgcn_mfma_f32_16x16x32_bf16(afr, bl, accl[nf], 0, 0, 0);
            accr[nf] = __builtin_amdgcn_mfma_f32_16x16x32_bf16(afr, br, accr[nf], 0, 0, 0);
        }
    }

    // C/D layout: col=lane&15, row=(lane>>4)*4+reg   [m89-verified]
#pragma unroll
    for (int nf = 0; nf < 4; ++nf) {
        const int col = nf * 16 + lr;
        const float bv = bias[col];
#pragma unroll
        for (int j = 0; j < 4; ++j) {
            const int row = row0 + lg * 4 + j;
            if (row < nN) {
                xl[(size_t)row * 64 + col] = (unsigned short)f2bf(accl[nf][j]);
                xr[(size_t)row * 64 + col] = accr[nf][j] + bv;
            }
        }
    }
}

// ----------------------------- gather-mean v6 --------------------------------
// one wave per node; lane = feature (2B). csr segment bounds forced into SGPRs;
// csr[i+j] with uniform address -> s_load (scalar cache); per-edge address is
// SGPR base + constant lane voffset. csr holds byte offsets (src<<7).
template<bool DOELU>
__global__ void gather_kernel(const unsigned short* __restrict__ xl,
                              const float* __restrict__ xr,
                              const int* __restrict__ rowptr, const int* __restrict__ csr,
                              unsigned short* __restrict__ outp, int nN, int nE) {
    const int node = blockIdx.x * (blockDim.x >> 6) + (threadIdx.x >> 6);
    if (node >= nN) return;
    const int lane = threadIdx.x & 63;
    int b = rowptr[node];
    int e = rowptr[node + 1];
    b = max(0, min(b, nE));
    e = max(b, min(e, nE));
    b = __builtin_amdgcn_readfirstlane(b);
    e = __builtin_amdgcn_readfirstlane(e);
    const float d = (float)(e - b);
    const char* xlb = (const char*)xl + (lane << 1);

    float acc = 0.f;
    int i = b;
    // full batches of 16 — indices via scalar loads (uniform addresses)
    for (; i + 16 <= e; i += 16) {
        unsigned short v[16];
#pragma unroll
        for (int j = 0; j < 16; ++j) {
            const unsigned s = (unsigned)csr[i + j];       // s_load (uniform)
            v[j] = *(const unsigned short*)(xlb + s);
        }
#pragma unroll
        for (int j = 0; j < 16; ++j) acc += b2f(v[j]);
    }
    // tail batch (clamped scalar loads, predicated adds)
    if (i < e) {
        const int lim = e - i;       // 1..15
        unsigned short v[16];
#pragma unroll
        for (int j = 0; j < 16; ++j) {
            const unsigned s = (unsigned)csr[i + min(j, lim - 1)];
            v[j] = *(const unsigned short*)(xlb + s);
        }
#pragma unroll
        for (int j = 0; j < 16; ++j) acc += (j < lim) ? b2f(v[j]) : 0.f;
    }

    float vout = acc / fmaxf(d, 1.0f) + xr[(size_t)node * 64 + lane];
    if (DOELU) vout = vout > 0.f ? vout : expm1f(vout);
    outp[(size_t)node * 64 + lane] = (unsigned short)f2bf(vout);
}

// ----------------------------- head (fp32 VALU, bf16 A) ----------------------
template<int F, int NOUT>
__global__ void head_kernel(const unsigned short* __restrict__ A,
                            const float* __restrict__ W,
                            const float* __restrict__ bias,
                            float* __restrict__ out, int nN) {
    constexpr int NCH = F / 32;
    __shared__ float As[64][36];
    __shared__ float Bs[32][64];

    const int t = threadIdx.x;
    const int block0 = blockIdx.x * 64;
    const int tm = (t >> 4) << 2;
    const int tn = (t & 15) << 2;

    float acc[4][4] = {};

    for (int ch = 0; ch < NCH; ++ch) {
        const int kg0 = ch * 32;
        {
            const int kk = (t & 7) * 4;
#pragma unroll
            for (int r = 0; r < 2; ++r) {
                const int n = (t >> 3) + r * 32;
                const int node = block0 + n;
                float4 v = make_float4(0.f, 0.f, 0.f, 0.f);
                if (node < nN) {
                    const us4 u = *reinterpret_cast<const us4*>(A + (size_t)node * F + kg0 + kk);
                    v.x = b2f(u[0]); v.y = b2f(u[1]); v.z = b2f(u[2]); v.w = b2f(u[3]);
                }
                *reinterpret_cast<float4*>(&As[n][kk]) = v;
            }
        }
        {
            const int j = t & 63;
#pragma unroll
            for (int p = 0; p < 8; ++p) {
                const int kk = (t >> 6) + p * 4;
                Bs[kk][j] = (j < NOUT) ? W[(size_t)j * F + kg0 + kk] : 0.0f;
            }
        }
        __syncthreads();
#pragma unroll
        for (int kk = 0; kk < 32; ++kk) {
            const float a0 = As[tm + 0][kk];
            const float a1 = As[tm + 1][kk];
            const float a2 = As[tm + 2][kk];
            const float a3 = As[tm + 3][kk];
            const float4 bv = *reinterpret_cast<const float4*>(&Bs[kk][tn]);
            acc[0][0] += a0 * bv.x; acc[0][1] += a0 * bv.y; acc[0][2] += a0 * bv.z; acc[0][3] += a0 * bv.w;
            acc[1][0] += a1 * bv.x; acc[1][1] += a1 * bv.y; acc[1][2] += a1 * bv.z; acc[1][3] += a1 * bv.w;
            acc[2][0] += a2 * bv.x; acc[2][1] += a2 * bv.y; acc[2][2] += a2 * bv.z; acc[2][3] += a2 * bv.w;
            acc[3][0] += a3 * bv.x; acc[3][1] += a3 * bv.y; acc[3][2] += a3 * bv.z; acc[3][3] += a3 * bv.w;
        }
        __syncthreads();
    }

#pragma unroll
    for (int i = 0; i < 4; ++i) {
        const int node = block0 + tm + i;
        if (node >= nN) continue;
#pragma unroll
        for (int j = 0; j < 4; ++j) {
            const int col = tn + j;
            if (col < NOUT)
                out[(size_t)node * NOUT + col] = acc[i][j] + bias[col];
        }
    }
}

// ----------------------------- launch ---------------------------------------

extern "C" void kernel_launch(void* const* d_in, const int* in_sizes, int n_in,
                              void* d_out, int out_size, void* d_ws, size_t ws_size,
                              hipStream_t stream) {
    const float* x    = (const float*)d_in[0];
    const int*   ei   = (const int*)d_in[1];
    const float* W1l  = (const float*)d_in[2];
    const float* b1   = (const float*)d_in[3];
    const float* W1r  = (const float*)d_in[4];
    const float* W2l  = (const float*)d_in[5];
    const float* b2   = (const float*)d_in[6];
    const float* W2r  = (const float*)d_in[7];
    const float* W3l  = (const float*)d_in[8];
    const float* b3   = (const float*)d_in[9];
    const float* W3r  = (const float*)d_in[10];
    const float* Wout = (const float*)d_in[11];
    const float* bout = (const float*)d_in[12];

    const int N = in_sizes[0] / 128;   // 100000
    const int E = in_sizes[1] / 2;     // 1600000
    const int* src  = ei;
    const int* dstA = ei + E;
    const int nbc = (N + 1023) >> 10;

    char* ws = (char*)d_ws;
    size_t o = 0;
    int* bcur    = (int*)(ws + o); o += ws_align((size_t)MAXBC * 4);
    int* bbase   = (int*)(ws + o); o += ws_align((size_t)MAXBC * 4);
    int* rowptr  = (int*)(ws + o); o += ws_align((size_t)(N + 1) * 4);
    int* csr     = (int*)(ws + o); o += ws_align((size_t)E * 4);
    unsigned* ebuf = (unsigned*)(ws + o); o += ws_align((size_t)MAXBC * EB_CAP * 4);
    unsigned short* fw  = (unsigned short*)(ws + o); o += ws_align((size_t)32768 * 2);
    unsigned short* xl  = (unsigned short*)(ws + o); o += ws_align((size_t)N * 64 * 2);
    float*          xr  = (float*)(ws + o);          o += ws_align((size_t)N * 64 * 4);
    unsigned short* hAb = (unsigned short*)(ws + o); o += ws_align((size_t)N * 64 * 2);
    unsigned short* hBb = (unsigned short*)(ws + o); o += ws_align((size_t)N * 64 * 2);
    unsigned short* h3b = (unsigned short*)(ws + o); o += ws_align((size_t)N * 64 * 2);
    float* outp = (float*)d_out;

    const int projGrid = (N + 63) / 64;
    const int gatherGrid = (N + 3) / 4;
    const int headGrid = (N + 63) / 64;

    // ---- weight prep + CSR build ----
    zero_kernel<<<1, 256, 0, stream>>>(bcur, MAXBC);
    prep_all<<<128, 256, 0, stream>>>(W1l, W1r, W2l, W2r, W3l, W3r, fw);
    pass1_bin<<<(E + 4095) / 4096, 256, 0, stream>>>(src, dstA, bcur, ebuf, E, N, nbc);
    scan_buckets<<<1, 256, 0, stream>>>(bcur, bbase, nbc);
    pass2_build<<<nbc, 256, 0, stream>>>(ebuf, bcur, bbase, rowptr, csr, N, nbc);

    const unsigned short* fw1l = fw;
    const unsigned short* fw1r = fw + 8192;
    const unsigned short* fw2l = fw + 16384;
    const unsigned short* fw2r = fw + 16384 + 4096;
    const unsigned short* fw3l = fw + 16384 + 8192;
    const unsigned short* fw3r = fw + 16384 + 12288;

    // ---- layer 1 (128 -> 64, ELU) ----
    proj2_mfma<128, true><<<projGrid, 256, 0, stream>>>(x, fw1l, fw1r, b1, xl, xr, N);
    gather_kernel<true><<<gatherGrid, 256, 0, stream>>>(xl, xr, rowptr, csr, hAb, N, E);

    // ---- layer 2 (64 -> 64, ELU) ----
    proj2_mfma<64, false><<<projGrid, 256, 0, stream>>>(hAb, fw2l, fw2r, b2, xl, xr, N);
    gather_kernel<true><<<gatherGrid, 256, 0, stream>>>(xl, xr, rowptr, csr, hBb, N, E);

    // ---- layer 3 (64 -> 64, no ELU) ----
    proj2_mfma<64, false><<<projGrid, 256, 0, stream>>>(hBb, fw3l, fw3r, b3, xl, xr, N);
    gather_kernel<false><<<gatherGrid, 256, 0, stream>>>(xl, xr, rowptr, csr, h3b, N, E);

    // ---- head (64 -> 40, fp32 math, bf16 input) ----
    head_kernel<64, 40><<<headGrid, 256, 0, stream>>>(h3b, Wout, bout, outp, N);
}